// Round 2
// baseline (695.319 us; speedup 1.0000x reference)
//
#include <hip/hip_runtime.h>
#include <hip/hip_bf16.h>
#include <stdint.h>

#define N_NODES 50000
#define N_EDGES 800000
#define IN_DIM 1280
#define HID 512
#define EMB 64
#define M_PAD 50048   // 391 * 128
#define MT1 391
#define LN_EPS 1e-5f

typedef __attribute__((ext_vector_type(8))) __bf16 bf16x8;
typedef __attribute__((ext_vector_type(4))) float floatx4;

#define AS1C(p) ((const __attribute__((address_space(1))) void*)(p))
#define AS3(p)  ((__attribute__((address_space(3))) void*)(p))

__device__ __forceinline__ unsigned f2bf(float f) {
  unsigned u = __float_as_uint(f);
  u += 0x7FFFu + ((u >> 16) & 1u);
  return u >> 16;
}
__device__ __forceinline__ float bf2f(unsigned short s) {
  return __uint_as_float(((unsigned)s) << 16);
}

// ---------------- prep: weights -> bf16 transposed; LN-fold consts; zeros ------
// B1t[n][k] = W1[k][n]; Wgp[n][k] = ln_g[k]*Wg[k][n]; u[n]=b@Wg; v[n]=g@Wg
__global__ __launch_bounds__(256) void k_prep(const float* __restrict__ W1,
                                              const float* __restrict__ Wg,
                                              const float* __restrict__ ln_g,
                                              const float* __restrict__ ln_b,
                                              unsigned short* __restrict__ B1t,
                                              unsigned short* __restrict__ Wgp,
                                              float* __restrict__ uvec,
                                              float* __restrict__ vvec,
                                              int* __restrict__ deg,
                                              float* __restrict__ s1,
                                              float* __restrict__ s2) {
  int idx = blockIdx.x * 256 + threadIdx.x;
  if (idx < HID * IN_DIM) {
    int n = idx / IN_DIM;
    int k = idx - n * IN_DIM;
    B1t[idx] = (unsigned short)f2bf(W1[(size_t)k * HID + n]);
  }
  if (idx < EMB * HID) {
    int n = idx >> 9;
    int k = idx & 511;
    Wgp[idx] = (unsigned short)f2bf(ln_g[k] * Wg[(size_t)k * EMB + n]);
  }
  if (idx < EMB) {
    float su = 0.f, sv = 0.f;
    for (int k = 0; k < HID; ++k) {
      float wv = Wg[(size_t)k * EMB + idx];
      su += ln_b[k] * wv;
      sv += ln_g[k] * wv;
    }
    uvec[idx] = su;
    vvec[idx] = sv;
  }
  if (idx < N_NODES) deg[idx] = 0;
  if (idx < M_PAD) { s1[idx] = 0.f; s2[idx] = 0.f; }
}

// ---------------- conv (features fp32->bf16, pad zero) + hist fused ------------
__global__ __launch_bounds__(256) void k_convhist(const float* __restrict__ F,
                                                  unsigned short* __restrict__ Fb,
                                                  const int* __restrict__ dst,
                                                  int* __restrict__ deg) {
  if (blockIdx.x < 31280) {
    size_t base = ((size_t)blockIdx.x * 256 + threadIdx.x) * 8;
    uint4 o;
    if (base < (size_t)N_NODES * IN_DIM) {
      float4 f0 = *(const float4*)(F + base);
      float4 f1 = *(const float4*)(F + base + 4);
      o.x = f2bf(f0.x) | (f2bf(f0.y) << 16);
      o.y = f2bf(f0.z) | (f2bf(f0.w) << 16);
      o.z = f2bf(f1.x) | (f2bf(f1.y) << 16);
      o.w = f2bf(f1.z) | (f2bf(f1.w) << 16);
    } else {
      o = make_uint4(0u, 0u, 0u, 0u);
    }
    *(uint4*)(Fb + base) = o;
  } else {
    int t = (blockIdx.x - 31280) * 256 + threadIdx.x;
    if (t < N_EDGES) atomicAdd(&deg[dst[t]], 1);
  }
}

// ---------------- GEMM1: x = relu(Fb @ W1 + b1) -> bf16; row stats -------------
// Counted-vmcnt 2-phase double-buffer: issue tile k+1's 8 global_load_lds, then
// s_waitcnt vmcnt(8) (drain only tile k) + raw s_barrier. HBM latency of k+1
// overlaps compute of k. LDS chunk swizzle unchanged from verified baseline.
// Grid: 1D 1564 with bijective chunked XCD map so the 4 bn-siblings of each
// A-tile land on the same XCD's L2 (A fetched from HBM once).
__global__ __launch_bounds__(256) void k_gemm1(const unsigned short* __restrict__ Abf,
                                               const unsigned short* __restrict__ Bt,
                                               const float* __restrict__ bias1,
                                               unsigned short* __restrict__ xn,
                                               float* __restrict__ s1,
                                               float* __restrict__ s2) {
  __shared__ unsigned short As[2 * 128 * 64];   // 2 x 16 KB
  __shared__ unsigned short Bs[2 * 128 * 64];   // 2 x 16 KB
  const int t = threadIdx.x;
  // chunked XCD swizzle (bijective for nwg=1564, 8 XCDs): lin = chunkstart(xcd)+pos
  const int o = blockIdx.x;
  const int xcd = o & 7, pos = o >> 3;
  const int lin = (xcd < 4 ? xcd * 196 : 784 + (xcd - 4) * 195) + pos;
  const int bm = lin >> 2, bn = lin & 3;
  const int w = t >> 6, lane = t & 63, quad = lane >> 4, lr = lane & 15;
  const int wm = (w & 1) * 64, wn = (w >> 1) * 64;

  floatx4 acc[4][4];
#pragma unroll
  for (int i = 0; i < 4; ++i)
#pragma unroll
    for (int j = 0; j < 4; ++j) acc[i][j] = (floatx4){0.f, 0.f, 0.f, 0.f};

  // staging: issue j covers LDS chunks j*256 + t  (chunk = row*8 + storecol)
  // row = j*32 + (t>>3), storecol = t&7, source chunk = (t&7) ^ ((t>>3)&7)
  const int rr = t >> 3;
  const int cc = (t & 7) ^ (rr & 7);
  const unsigned short* aP[4];
  const unsigned short* bP[4];
#pragma unroll
  for (int j = 0; j < 4; ++j) {
    aP[j] = Abf + (size_t)(bm * 128 + j * 32 + rr) * IN_DIM + cc * 8;
    bP[j] = Bt + (size_t)(bn * 128 + j * 32 + rr) * IN_DIM + cc * 8;
  }
  const int woff = w * 512;                 // wave base: 64 lanes * 16B = 1024B
  const int l7 = lr & 7;

#define STAGE1(K0, BUF) do {                                                        \
    unsigned short* aw = As + (BUF) * 8192 + woff;                                  \
    unsigned short* bw = Bs + (BUF) * 8192 + woff;                                  \
    _Pragma("unroll")                                                               \
    for (int j = 0; j < 4; ++j) {                                                   \
      __builtin_amdgcn_global_load_lds(AS1C(aP[j] + (K0)), AS3(aw + j * 2048), 16, 0, 0); \
      __builtin_amdgcn_global_load_lds(AS1C(bP[j] + (K0)), AS3(bw + j * 2048), 16, 0, 0); \
    } } while (0)

  STAGE1(0, 0);
  for (int it = 0; it < 20; ++it) {           // 20 = IN_DIM/64 K-steps
    const int cur = it & 1;
    if (it + 1 < 20) {
      STAGE1((it + 1) * 64, cur ^ 1);
      asm volatile("s_waitcnt vmcnt(8)" ::: "memory");   // drain tile `it` only
    } else {
      asm volatile("s_waitcnt vmcnt(0)" ::: "memory");
    }
    __builtin_amdgcn_s_barrier();
    asm volatile("" ::: "memory");
    __builtin_amdgcn_sched_barrier(0);

    const unsigned short* Ab = As + cur * 8192;
    const unsigned short* Bb = Bs + cur * 8192;
#pragma unroll
    for (int h = 0; h < 2; ++h) {
      const int col = ((h * 4 + quad) ^ l7) * 8;
      bf16x8 af[4], bfv[4];
#pragma unroll
      for (int mi = 0; mi < 4; ++mi)
        af[mi] = *(const bf16x8*)&Ab[(wm + mi * 16 + lr) * 64 + col];
#pragma unroll
      for (int ni = 0; ni < 4; ++ni)
        bfv[ni] = *(const bf16x8*)&Bb[(wn + ni * 16 + lr) * 64 + col];
#pragma unroll
      for (int mi = 0; mi < 4; ++mi)
#pragma unroll
        for (int ni = 0; ni < 4; ++ni)
          acc[mi][ni] = __builtin_amdgcn_mfma_f32_16x16x32_bf16(af[mi], bfv[ni], acc[mi][ni], 0, 0, 0);
    }
    asm volatile("" ::: "memory");
    __builtin_amdgcn_s_barrier();             // buf[cur] free for tile it+2
  }
#undef STAGE1

  // epilogue: bias + ReLU -> bf16 xn; per-row partial sums (of the rounded
  // values, 64 cols per wave) -> atomicAdd into s1/s2
#pragma unroll
  for (int mi = 0; mi < 4; ++mi) {
    int gr = bm * 128 + wm + mi * 16 + quad * 4;
#pragma unroll
    for (int r = 0; r < 4; ++r) {
      float ps1 = 0.f, ps2 = 0.f;
#pragma unroll
      for (int ni = 0; ni < 4; ++ni) {
        int gc = bn * 128 + wn + ni * 16 + lr;
        float v = acc[mi][ni][r] + bias1[gc];
        v = v > 0.f ? v : 0.f;
        unsigned short h = (unsigned short)f2bf(v);
        xn[(size_t)(gr + r) * HID + gc] = h;
        float vr = bf2f(h);
        ps1 += vr;
        ps2 += vr * vr;
      }
#pragma unroll
      for (int m = 1; m < 16; m <<= 1) {
        ps1 += __shfl_xor(ps1, m, 64);
        ps2 += __shfl_xor(ps2, m, 64);
      }
      if (lr == 0) {
        atomicAdd(&s1[gr + r], ps1);
        atomicAdd(&s2[gr + r], ps2);
      }
    }
  }
}

// swizzle for BK=32 tiles (gemm2): chunk c of row r at c ^ swz(r), 4 chunks/row
__device__ __forceinline__ int swz(int r) { return (r ^ (r >> 2)) & 3; }

// ---------------- GEMM2 (LN folded) + fused el/er ------------------------------
// feat[r][n] = rs_r * (x[r] @ Wgp)[n] + u[n] - mu_r*rs_r*v[n]
// Same counted-vmcnt 2-phase double-buffer (3 loads/wave -> vmcnt(3)).
__global__ __launch_bounds__(256) void k_gemm2(const unsigned short* __restrict__ Xn,
                                               const unsigned short* __restrict__ Wgp,
                                               const float* __restrict__ s1,
                                               const float* __restrict__ s2,
                                               const float* __restrict__ uvec,
                                               const float* __restrict__ vvec,
                                               const float* __restrict__ al,
                                               const float* __restrict__ ar,
                                               float* __restrict__ feat,
                                               float* __restrict__ el,
                                               float* __restrict__ er) {
  __shared__ unsigned short As[2 * 128 * 32];   // 2 x 8 KB
  __shared__ unsigned short Bs[2 * 64 * 32];    // 2 x 4 KB
  const int t = threadIdx.x;
  const int bm = blockIdx.x;
  const int w = t >> 6, lane = t & 63, quad = lane >> 4, lr = lane & 15;

  floatx4 acc[2][4];
#pragma unroll
  for (int i = 0; i < 2; ++i)
#pragma unroll
    for (int j = 0; j < 4; ++j) acc[i][j] = (floatx4){0.f, 0.f, 0.f, 0.f};

  const int r0 = t >> 2, c0 = (t & 3) ^ swz(t >> 2);
  const int r1 = 64 + (t >> 2), c1 = (t & 3) ^ swz(64 + (t >> 2));
  const unsigned short* a0 = Xn + (size_t)(bm * 128 + r0) * HID + c0 * 8;
  const unsigned short* a1 = Xn + (size_t)(bm * 128 + r1) * HID + c1 * 8;
  const unsigned short* b0 = Wgp + (size_t)r0 * HID + c0 * 8;
  const int woff = w * 512;                 // wave covers 1024 B

  const int q2 = quad ^ swz(lr);

#define STAGE2(K0, BUF) do {                                                        \
    unsigned short* aw = As + (BUF) * 4096 + woff;                                  \
    unsigned short* bw = Bs + (BUF) * 2048 + woff;                                  \
    __builtin_amdgcn_global_load_lds(AS1C(a0 + (K0)), AS3(aw), 16, 0, 0);           \
    __builtin_amdgcn_global_load_lds(AS1C(a1 + (K0)), AS3(aw + 2048), 16, 0, 0);    \
    __builtin_amdgcn_global_load_lds(AS1C(b0 + (K0)), AS3(bw), 16, 0, 0);           \
  } while (0)

  STAGE2(0, 0);
  for (int it = 0; it < 16; ++it) {           // 16 = HID/32 K-steps
    const int cur = it & 1;
    if (it + 1 < 16) {
      STAGE2((it + 1) * 32, cur ^ 1);
      asm volatile("s_waitcnt vmcnt(3)" ::: "memory");
    } else {
      asm volatile("s_waitcnt vmcnt(0)" ::: "memory");
    }
    __builtin_amdgcn_s_barrier();
    asm volatile("" ::: "memory");
    __builtin_amdgcn_sched_barrier(0);

    const unsigned short* Ab = As + cur * 4096;
    const unsigned short* Bb = Bs + cur * 2048;
    bf16x8 af[2], bfv[4];
#pragma unroll
    for (int mi = 0; mi < 2; ++mi)
      af[mi] = *(const bf16x8*)&Ab[(w * 32 + mi * 16 + lr) * 32 + q2 * 8];
#pragma unroll
    for (int ni = 0; ni < 4; ++ni)
      bfv[ni] = *(const bf16x8*)&Bb[(ni * 16 + lr) * 32 + q2 * 8];
#pragma unroll
    for (int mi = 0; mi < 2; ++mi)
#pragma unroll
      for (int ni = 0; ni < 4; ++ni)
        acc[mi][ni] = __builtin_amdgcn_mfma_f32_16x16x32_bf16(af[mi], bfv[ni], acc[mi][ni], 0, 0, 0);
    asm volatile("" ::: "memory");
    __builtin_amdgcn_s_barrier();
  }
#undef STAGE2

  float alv[4], arv[4], uv[4], vv[4];
#pragma unroll
  for (int ni = 0; ni < 4; ++ni) {
    alv[ni] = al[ni * 16 + lr];
    arv[ni] = ar[ni * 16 + lr];
    uv[ni] = uvec[ni * 16 + lr];
    vv[ni] = vvec[ni * 16 + lr];
  }
#pragma unroll
  for (int mi = 0; mi < 2; ++mi) {
    int gr = bm * 128 + w * 32 + mi * 16 + quad * 4;
#pragma unroll
    for (int r = 0; r < 4; ++r) {
      int row = gr + r;
      float mu = s1[row] * (1.f / HID);
      float rs = rsqrtf(s2[row] * (1.f / HID) - mu * mu + LN_EPS);
      float mrs = mu * rs;
      float sl = 0.f, sr2 = 0.f;
#pragma unroll
      for (int ni = 0; ni < 4; ++ni) {
        float v = rs * acc[mi][ni][r] + uv[ni] - mrs * vv[ni];
        feat[(size_t)row * EMB + ni * 16 + lr] = v;
        sl += v * alv[ni];
        sr2 += v * arv[ni];
      }
#pragma unroll
      for (int m = 1; m < 16; m <<= 1) {
        sl += __shfl_xor(sl, m, 64);
        sr2 += __shfl_xor(sr2, m, 64);
      }
      if (lr == 0) {
        el[row] = sl;
        er[row] = sr2;
      }
    }
  }
}

// ---------------- CSR build ----------------------------------------------------
__global__ __launch_bounds__(256) void k_scan1(const int* __restrict__ deg,
                                               int* __restrict__ rowstart,
                                               int* __restrict__ bsum) {
  __shared__ int sh[256];
  int t = threadIdx.x, i = blockIdx.x * 256 + t;
  int x = (i < N_NODES) ? deg[i] : 0;
  sh[t] = x;
  __syncthreads();
  for (int off = 1; off < 256; off <<= 1) {
    int v = (t >= off) ? sh[t - off] : 0;
    __syncthreads();
    sh[t] += v;
    __syncthreads();
  }
  if (i < N_NODES) rowstart[i] = sh[t] - x;
  if (t == 255) bsum[blockIdx.x] = sh[255];
}

// each block redundantly scans the 196 block sums, applies its own offset
__global__ __launch_bounds__(256) void k_scan23(const int* __restrict__ bsum,
                                                int* __restrict__ rowstart,
                                                int* __restrict__ cursor) {
  __shared__ int sh[256];
  int t = threadIdx.x;
  int x = (t < 196) ? bsum[t] : 0;
  sh[t] = x;
  __syncthreads();
  for (int off = 1; off < 256; off <<= 1) {
    int v = (t >= off) ? sh[t - off] : 0;
    __syncthreads();
    sh[t] += v;
    __syncthreads();
  }
  int boff = (blockIdx.x > 0) ? sh[blockIdx.x - 1] : 0;  // exclusive prefix
  __syncthreads();
  int i = blockIdx.x * 256 + t;
  if (i < N_NODES) {
    int rs = rowstart[i] + boff;
    rowstart[i] = rs;
    cursor[i] = rs;
  }
}

__global__ __launch_bounds__(256) void k_fill(const int* __restrict__ src,
                                              const int* __restrict__ dst,
                                              int* __restrict__ cursor,
                                              int* __restrict__ csr_src) {
  int t = blockIdx.x * 256 + threadIdx.x;
  if (t >= N_EDGES) return;
  int pos = atomicAdd(&cursor[dst[t]], 1);
  csr_src[pos] = src[t];
}

// ---------------- GAT aggregation, wave per node, no-max softmax ---------------
// |e| <= ~15 with this data (el,er are 64-dim dots with 0.1-scale attn vecs),
// so exp(e) is safe in fp32 and exp(e)/sum(exp(e)) == softmax exactly.
__global__ __launch_bounds__(256) void k_gat(const int* __restrict__ rowstart,
                                             const int* __restrict__ deg,
                                             const int* __restrict__ csr_src,
                                             const float* __restrict__ el,
                                             const float* __restrict__ er,
                                             const float* __restrict__ feat,
                                             const float* __restrict__ bias_g,
                                             float* __restrict__ out) {
  int w = threadIdx.x >> 6, lane = threadIdx.x & 63;
  int v = blockIdx.x * 4 + w;
  int start = rowstart[v], d = deg[v];
  float erv = er[v];
  float s = 0.f, O = 0.f;
#pragma unroll 4
  for (int i = 0; i < d; ++i) {
    int sv = csr_src[start + i];
    float f = feat[(size_t)sv * EMB + lane];
    float e = el[sv] + erv;
    e = e > 0.f ? e : 0.2f * e;
    float p = __expf(e);
    s += p;
    O = fmaf(p, f, O);
  }
  out[(size_t)v * EMB + lane] = (d > 0 ? O / s : 0.f) + bias_g[lane];
}

extern "C" void kernel_launch(void* const* d_in, const int* in_sizes, int n_in,
                              void* d_out, int out_size, void* d_ws, size_t ws_size,
                              hipStream_t stream) {
  const float* features = (const float*)d_in[0];
  const int* src        = (const int*)d_in[1];
  const int* dst        = (const int*)d_in[2];
  const float* W1       = (const float*)d_in[3];
  const float* b1       = (const float*)d_in[4];
  const float* ln_g     = (const float*)d_in[5];
  const float* ln_b     = (const float*)d_in[6];
  const float* Wg       = (const float*)d_in[7];
  const float* attn_l   = (const float*)d_in[8];
  const float* attn_r   = (const float*)d_in[9];
  const float* bias_g   = (const float*)d_in[10];
  float* out = (float*)d_out;

  char* ws = (char*)d_ws;
  size_t off = 0;
  auto alloc = [&](size_t bytes) {
    char* p = ws + off;
    off = (off + bytes + 255) & ~(size_t)255;
    return p;
  };
  unsigned short* B1t   = (unsigned short*)alloc((size_t)HID * IN_DIM * 2);
  unsigned short* Wgp   = (unsigned short*)alloc((size_t)EMB * HID * 2);
  unsigned short* featbf= (unsigned short*)alloc((size_t)M_PAD * IN_DIM * 2);
  unsigned short* xn    = (unsigned short*)alloc((size_t)M_PAD * HID * 2);
  float* feat           = (float*)alloc((size_t)M_PAD * EMB * 4);
  float* el             = (float*)alloc((size_t)M_PAD * 4);
  float* er             = (float*)alloc((size_t)M_PAD * 4);
  float* s1             = (float*)alloc((size_t)M_PAD * 4);
  float* s2             = (float*)alloc((size_t)M_PAD * 4);
  float* uvec           = (float*)alloc(EMB * 4);
  float* vvec           = (float*)alloc(EMB * 4);
  int* deg              = (int*)alloc((size_t)N_NODES * 4);
  int* rowstart         = (int*)alloc((size_t)N_NODES * 4);
  int* cursor           = (int*)alloc((size_t)N_NODES * 4);
  int* bsum             = (int*)alloc(256 * 4);
  int* csr_src          = (int*)alloc((size_t)N_EDGES * 4);
  (void)ws_size; (void)in_sizes; (void)n_in; (void)out_size;

  k_prep<<<dim3(2560), dim3(256), 0, stream>>>(W1, Wg, ln_g, ln_b, B1t, Wgp,
                                               uvec, vvec, deg, s1, s2);
  k_convhist<<<dim3(31280 + 3125), dim3(256), 0, stream>>>(features, featbf, dst, deg);
  k_scan1<<<dim3(196), dim3(256), 0, stream>>>(deg, rowstart, bsum);
  k_scan23<<<dim3(196), dim3(256), 0, stream>>>(bsum, rowstart, cursor);
  k_fill<<<dim3(3125), dim3(256), 0, stream>>>(src, dst, cursor, csr_src);
  k_gemm1<<<dim3(1564), dim3(256), 0, stream>>>(featbf, B1t, b1, xn, s1, s2);
  k_gemm2<<<dim3(MT1), dim3(256), 0, stream>>>(xn, Wgp, s1, s2, uvec, vvec,
                                               attn_l, attn_r, feat, el, er);
  k_gat<<<dim3(12500), dim3(256), 0, stream>>>(rowstart, deg, csr_src, el, er, feat, bias_g, out);
}

// Round 3
// 688.707 us; speedup vs baseline: 1.0096x; 1.0096x over previous
//
#include <hip/hip_runtime.h>
#include <hip/hip_bf16.h>
#include <stdint.h>

#define N_NODES 50000
#define N_EDGES 800000
#define IN_DIM 1280
#define HID 512
#define EMB 64
#define M_PAD 50048   // 391 * 128
#define MT1 391
#define LN_EPS 1e-5f

typedef __attribute__((ext_vector_type(8))) __bf16 bf16x8;
typedef __attribute__((ext_vector_type(4))) float floatx4;

#define AS1C(p) ((const __attribute__((address_space(1))) void*)(p))
#define AS3(p)  ((__attribute__((address_space(3))) void*)(p))

__device__ __forceinline__ unsigned f2bf(float f) {
  unsigned u = __float_as_uint(f);
  u += 0x7FFFu + ((u >> 16) & 1u);
  return u >> 16;
}
__device__ __forceinline__ float bf2f(unsigned short s) {
  return __uint_as_float(((unsigned)s) << 16);
}

// ---------------- prep: weights -> bf16 transposed; LN-fold consts; zeros ------
// B1t[n][k] = W1[k][n]; Wgp[n][k] = ln_g[k]*Wg[k][n]; u[n]=b@Wg; v[n]=g@Wg
__global__ __launch_bounds__(256) void k_prep(const float* __restrict__ W1,
                                              const float* __restrict__ Wg,
                                              const float* __restrict__ ln_g,
                                              const float* __restrict__ ln_b,
                                              unsigned short* __restrict__ B1t,
                                              unsigned short* __restrict__ Wgp,
                                              float* __restrict__ uvec,
                                              float* __restrict__ vvec,
                                              int* __restrict__ deg,
                                              float* __restrict__ s1,
                                              float* __restrict__ s2) {
  int idx = blockIdx.x * 256 + threadIdx.x;
  if (idx < HID * IN_DIM) {
    int n = idx / IN_DIM;
    int k = idx - n * IN_DIM;
    B1t[idx] = (unsigned short)f2bf(W1[(size_t)k * HID + n]);
  }
  if (idx < EMB * HID) {
    int n = idx >> 9;
    int k = idx & 511;
    Wgp[idx] = (unsigned short)f2bf(ln_g[k] * Wg[(size_t)k * EMB + n]);
  }
  if (idx < EMB) {
    float su = 0.f, sv = 0.f;
    for (int k = 0; k < HID; ++k) {
      float wv = Wg[(size_t)k * EMB + idx];
      su += ln_b[k] * wv;
      sv += ln_g[k] * wv;
    }
    uvec[idx] = su;
    vvec[idx] = sv;
  }
  if (idx < N_NODES) deg[idx] = 0;
  if (idx < M_PAD) { s1[idx] = 0.f; s2[idx] = 0.f; }
}

// ---------------- conv (features fp32->bf16, pad zero) + hist fused ------------
__global__ __launch_bounds__(256) void k_convhist(const float* __restrict__ F,
                                                  unsigned short* __restrict__ Fb,
                                                  const int* __restrict__ dst,
                                                  int* __restrict__ deg) {
  if (blockIdx.x < 31280) {
    size_t base = ((size_t)blockIdx.x * 256 + threadIdx.x) * 8;
    uint4 o;
    if (base < (size_t)N_NODES * IN_DIM) {
      float4 f0 = *(const float4*)(F + base);
      float4 f1 = *(const float4*)(F + base + 4);
      o.x = f2bf(f0.x) | (f2bf(f0.y) << 16);
      o.y = f2bf(f0.z) | (f2bf(f0.w) << 16);
      o.z = f2bf(f1.x) | (f2bf(f1.y) << 16);
      o.w = f2bf(f1.z) | (f2bf(f1.w) << 16);
    } else {
      o = make_uint4(0u, 0u, 0u, 0u);
    }
    *(uint4*)(Fb + base) = o;
  } else {
    int t = (blockIdx.x - 31280) * 256 + threadIdx.x;
    if (t < N_EDGES) atomicAdd(&deg[dst[t]], 1);
  }
}

// ---------------- GEMM1: x = relu(Fb @ W1 + b1) -> bf16; row stats -------------
// Round-1 verified single-buffer loop (32 KB LDS, TLP-hidden latency) + the
// round-2-verified bijective chunked XCD swizzle (bn-siblings of an A-tile on
// one XCD's L2: FETCH 259 MB -> 83 MB, per-iter stall ~900cy HBM -> ~L2-hit).
__global__ __launch_bounds__(256) void k_gemm1(const unsigned short* __restrict__ Abf,
                                               const unsigned short* __restrict__ Bt,
                                               const float* __restrict__ bias1,
                                               unsigned short* __restrict__ xn,
                                               float* __restrict__ s1,
                                               float* __restrict__ s2) {
  __shared__ unsigned short As[128 * 64];   // 16 KB
  __shared__ unsigned short Bs[128 * 64];   // 16 KB
  const int t = threadIdx.x;
  // chunked XCD swizzle (bijective for nwg=1564, 8 XCDs)
  const int o = blockIdx.x;
  const int xcd = o & 7, pos = o >> 3;
  const int lin = (xcd < 4 ? xcd * 196 : 784 + (xcd - 4) * 195) + pos;
  const int bm = lin >> 2, bn = lin & 3;
  const int w = t >> 6, lane = t & 63, quad = lane >> 4, lr = lane & 15;
  const int wm = (w & 1) * 64, wn = (w >> 1) * 64;

  floatx4 acc[4][4];
#pragma unroll
  for (int i = 0; i < 4; ++i)
#pragma unroll
    for (int j = 0; j < 4; ++j) acc[i][j] = (floatx4){0.f, 0.f, 0.f, 0.f};

  // staging: issue j covers LDS chunks j*256 + t  (chunk = row*8 + storecol)
  // row = j*32 + (t>>3), storecol = t&7, source chunk = (t&7) ^ ((t>>3)&7)
  const int rr = t >> 3;
  const int cc = (t & 7) ^ (rr & 7);
  const unsigned short* aP[4];
  const unsigned short* bP[4];
#pragma unroll
  for (int j = 0; j < 4; ++j) {
    aP[j] = Abf + (size_t)(bm * 128 + j * 32 + rr) * IN_DIM + cc * 8;
    bP[j] = Bt + (size_t)(bn * 128 + j * 32 + rr) * IN_DIM + cc * 8;
  }
  unsigned short* asw = As + w * 512;       // wave base: 64 lanes * 16B = 1024B
  unsigned short* bsw = Bs + w * 512;

  const int l7 = lr & 7;

  for (int k0 = 0; k0 < IN_DIM; k0 += 64) {
#pragma unroll
    for (int j = 0; j < 4; ++j) {
      __builtin_amdgcn_global_load_lds(AS1C(aP[j] + k0), AS3(asw + j * 2048), 16, 0, 0);
      __builtin_amdgcn_global_load_lds(AS1C(bP[j] + k0), AS3(bsw + j * 2048), 16, 0, 0);
    }
    __syncthreads();

#pragma unroll
    for (int h = 0; h < 2; ++h) {
      const int col = ((h * 4 + quad) ^ l7) * 8;
      bf16x8 af[4], bfv[4];
#pragma unroll
      for (int mi = 0; mi < 4; ++mi)
        af[mi] = *(const bf16x8*)&As[(wm + mi * 16 + lr) * 64 + col];
#pragma unroll
      for (int ni = 0; ni < 4; ++ni)
        bfv[ni] = *(const bf16x8*)&Bs[(wn + ni * 16 + lr) * 64 + col];
#pragma unroll
      for (int mi = 0; mi < 4; ++mi)
#pragma unroll
        for (int ni = 0; ni < 4; ++ni)
          acc[mi][ni] = __builtin_amdgcn_mfma_f32_16x16x32_bf16(af[mi], bfv[ni], acc[mi][ni], 0, 0, 0);
    }
    __syncthreads();
  }

  // epilogue: bias + ReLU -> bf16 xn; per-row partial sums (of the rounded
  // values, 64 cols per wave) -> atomicAdd into s1/s2
#pragma unroll
  for (int mi = 0; mi < 4; ++mi) {
    int gr = bm * 128 + wm + mi * 16 + quad * 4;
#pragma unroll
    for (int r = 0; r < 4; ++r) {
      float ps1 = 0.f, ps2 = 0.f;
#pragma unroll
      for (int ni = 0; ni < 4; ++ni) {
        int gc = bn * 128 + wn + ni * 16 + lr;
        float v = acc[mi][ni][r] + bias1[gc];
        v = v > 0.f ? v : 0.f;
        unsigned short h = (unsigned short)f2bf(v);
        xn[(size_t)(gr + r) * HID + gc] = h;
        float vr = bf2f(h);
        ps1 += vr;
        ps2 += vr * vr;
      }
#pragma unroll
      for (int m = 1; m < 16; m <<= 1) {
        ps1 += __shfl_xor(ps1, m, 64);
        ps2 += __shfl_xor(ps2, m, 64);
      }
      if (lr == 0) {
        atomicAdd(&s1[gr + r], ps1);
        atomicAdd(&s2[gr + r], ps2);
      }
    }
  }
}

// swizzle for BK=32 tiles (gemm2): chunk c of row r at c ^ swz(r), 4 chunks/row
__device__ __forceinline__ int swz(int r) { return (r ^ (r >> 2)) & 3; }

// ---------------- GEMM2 (LN folded) + fused el/er ------------------------------
// feat[r][n] = rs_r * (x[r] @ Wgp)[n] + u[n] - mu_r*rs_r*v[n]
__global__ __launch_bounds__(256) void k_gemm2(const unsigned short* __restrict__ Xn,
                                               const unsigned short* __restrict__ Wgp,
                                               const float* __restrict__ s1,
                                               const float* __restrict__ s2,
                                               const float* __restrict__ uvec,
                                               const float* __restrict__ vvec,
                                               const float* __restrict__ al,
                                               const float* __restrict__ ar,
                                               float* __restrict__ feat,
                                               float* __restrict__ el,
                                               float* __restrict__ er) {
  __shared__ unsigned short As[128 * 32];   // 8 KB
  __shared__ unsigned short Bs[64 * 32];    // 4 KB
  const int t = threadIdx.x;
  const int bm = blockIdx.x;
  const int w = t >> 6, lane = t & 63, quad = lane >> 4, lr = lane & 15;

  floatx4 acc[2][4];
#pragma unroll
  for (int i = 0; i < 2; ++i)
#pragma unroll
    for (int j = 0; j < 4; ++j) acc[i][j] = (floatx4){0.f, 0.f, 0.f, 0.f};

  const int r0 = t >> 2, c0 = (t & 3) ^ swz(t >> 2);
  const int r1 = 64 + (t >> 2), c1 = (t & 3) ^ swz(64 + (t >> 2));
  const unsigned short* a0 = Xn + (size_t)(bm * 128 + r0) * HID + c0 * 8;
  const unsigned short* a1 = Xn + (size_t)(bm * 128 + r1) * HID + c1 * 8;
  const unsigned short* b0 = Wgp + (size_t)r0 * HID + c0 * 8;
  unsigned short* asw = As + w * 512;
  unsigned short* bsw = Bs + w * 512;       // wave covers 1024 B

  const int q2 = quad ^ swz(lr);

  for (int k0 = 0; k0 < HID; k0 += 32) {
    __builtin_amdgcn_global_load_lds(AS1C(a0 + k0), AS3(asw), 16, 0, 0);
    __builtin_amdgcn_global_load_lds(AS1C(a1 + k0), AS3(asw + 2048), 16, 0, 0);
    __builtin_amdgcn_global_load_lds(AS1C(b0 + k0), AS3(bsw), 16, 0, 0);
    __syncthreads();

    bf16x8 af[2], bfv[4];
#pragma unroll
    for (int mi = 0; mi < 2; ++mi)
      af[mi] = *(const bf16x8*)&As[(w * 32 + mi * 16 + lr) * 32 + q2 * 8];
#pragma unroll
    for (int ni = 0; ni < 4; ++ni)
      bfv[ni] = *(const bf16x8*)&Bs[(ni * 16 + lr) * 32 + q2 * 8];
#pragma unroll
    for (int mi = 0; mi < 2; ++mi)
#pragma unroll
      for (int ni = 0; ni < 4; ++ni)
        acc[mi][ni] = __builtin_amdgcn_mfma_f32_16x16x32_bf16(af[mi], bfv[ni], acc[mi][ni], 0, 0, 0);
    __syncthreads();
  }

  float alv[4], arv[4], uv[4], vv[4];
#pragma unroll
  for (int ni = 0; ni < 4; ++ni) {
    alv[ni] = al[ni * 16 + lr];
    arv[ni] = ar[ni * 16 + lr];
    uv[ni] = uvec[ni * 16 + lr];
    vv[ni] = vvec[ni * 16 + lr];
  }
#pragma unroll
  for (int mi = 0; mi < 2; ++mi) {
    int gr = bm * 128 + w * 32 + mi * 16 + quad * 4;
#pragma unroll
    for (int r = 0; r < 4; ++r) {
      int row = gr + r;
      float mu = s1[row] * (1.f / HID);
      float rs = rsqrtf(s2[row] * (1.f / HID) - mu * mu + LN_EPS);
      float mrs = mu * rs;
      float sl = 0.f, sr2 = 0.f;
#pragma unroll
      for (int ni = 0; ni < 4; ++ni) {
        float v = rs * acc[mi][ni][r] + uv[ni] - mrs * vv[ni];
        feat[(size_t)row * EMB + ni * 16 + lr] = v;
        sl += v * alv[ni];
        sr2 += v * arv[ni];
      }
#pragma unroll
      for (int m = 1; m < 16; m <<= 1) {
        sl += __shfl_xor(sl, m, 64);
        sr2 += __shfl_xor(sr2, m, 64);
      }
      if (lr == 0) {
        el[row] = sl;
        er[row] = sr2;
      }
    }
  }
}

// ---------------- CSR build ----------------------------------------------------
__global__ __launch_bounds__(256) void k_scan1(const int* __restrict__ deg,
                                               int* __restrict__ rowstart,
                                               int* __restrict__ bsum) {
  __shared__ int sh[256];
  int t = threadIdx.x, i = blockIdx.x * 256 + t;
  int x = (i < N_NODES) ? deg[i] : 0;
  sh[t] = x;
  __syncthreads();
  for (int off = 1; off < 256; off <<= 1) {
    int v = (t >= off) ? sh[t - off] : 0;
    __syncthreads();
    sh[t] += v;
    __syncthreads();
  }
  if (i < N_NODES) rowstart[i] = sh[t] - x;
  if (t == 255) bsum[blockIdx.x] = sh[255];
}

// each block redundantly scans the 196 block sums, applies its own offset
__global__ __launch_bounds__(256) void k_scan23(const int* __restrict__ bsum,
                                                int* __restrict__ rowstart,
                                                int* __restrict__ cursor) {
  __shared__ int sh[256];
  int t = threadIdx.x;
  int x = (t < 196) ? bsum[t] : 0;
  sh[t] = x;
  __syncthreads();
  for (int off = 1; off < 256; off <<= 1) {
    int v = (t >= off) ? sh[t - off] : 0;
    __syncthreads();
    sh[t] += v;
    __syncthreads();
  }
  int boff = (blockIdx.x > 0) ? sh[blockIdx.x - 1] : 0;  // exclusive prefix
  __syncthreads();
  int i = blockIdx.x * 256 + t;
  if (i < N_NODES) {
    int rs = rowstart[i] + boff;
    rowstart[i] = rs;
    cursor[i] = rs;
  }
}

__global__ __launch_bounds__(256) void k_fill(const int* __restrict__ src,
                                              const int* __restrict__ dst,
                                              int* __restrict__ cursor,
                                              int* __restrict__ csr_src) {
  int t = blockIdx.x * 256 + threadIdx.x;
  if (t >= N_EDGES) return;
  int pos = atomicAdd(&cursor[dst[t]], 1);
  csr_src[pos] = src[t];
}

// ---------------- GAT aggregation, wave per node, no-max softmax ---------------
// |e| <= ~15 with this data (el,er are 64-dim dots with 0.1-scale attn vecs),
// so exp(e) is safe in fp32 and exp(e)/sum(exp(e)) == softmax exactly.
__global__ __launch_bounds__(256) void k_gat(const int* __restrict__ rowstart,
                                             const int* __restrict__ deg,
                                             const int* __restrict__ csr_src,
                                             const float* __restrict__ el,
                                             const float* __restrict__ er,
                                             const float* __restrict__ feat,
                                             const float* __restrict__ bias_g,
                                             float* __restrict__ out) {
  int w = threadIdx.x >> 6, lane = threadIdx.x & 63;
  int v = blockIdx.x * 4 + w;
  int start = rowstart[v], d = deg[v];
  float erv = er[v];
  float s = 0.f, O = 0.f;
#pragma unroll 4
  for (int i = 0; i < d; ++i) {
    int sv = csr_src[start + i];
    float f = feat[(size_t)sv * EMB + lane];
    float e = el[sv] + erv;
    e = e > 0.f ? e : 0.2f * e;
    float p = __expf(e);
    s += p;
    O = fmaf(p, f, O);
  }
  out[(size_t)v * EMB + lane] = (d > 0 ? O / s : 0.f) + bias_g[lane];
}

extern "C" void kernel_launch(void* const* d_in, const int* in_sizes, int n_in,
                              void* d_out, int out_size, void* d_ws, size_t ws_size,
                              hipStream_t stream) {
  const float* features = (const float*)d_in[0];
  const int* src        = (const int*)d_in[1];
  const int* dst        = (const int*)d_in[2];
  const float* W1       = (const float*)d_in[3];
  const float* b1       = (const float*)d_in[4];
  const float* ln_g     = (const float*)d_in[5];
  const float* ln_b     = (const float*)d_in[6];
  const float* Wg       = (const float*)d_in[7];
  const float* attn_l   = (const float*)d_in[8];
  const float* attn_r   = (const float*)d_in[9];
  const float* bias_g   = (const float*)d_in[10];
  float* out = (float*)d_out;

  char* ws = (char*)d_ws;
  size_t off = 0;
  auto alloc = [&](size_t bytes) {
    char* p = ws + off;
    off = (off + bytes + 255) & ~(size_t)255;
    return p;
  };
  unsigned short* B1t   = (unsigned short*)alloc((size_t)HID * IN_DIM * 2);
  unsigned short* Wgp   = (unsigned short*)alloc((size_t)EMB * HID * 2);
  unsigned short* featbf= (unsigned short*)alloc((size_t)M_PAD * IN_DIM * 2);
  unsigned short* xn    = (unsigned short*)alloc((size_t)M_PAD * HID * 2);
  float* feat           = (float*)alloc((size_t)M_PAD * EMB * 4);
  float* el             = (float*)alloc((size_t)M_PAD * 4);
  float* er             = (float*)alloc((size_t)M_PAD * 4);
  float* s1             = (float*)alloc((size_t)M_PAD * 4);
  float* s2             = (float*)alloc((size_t)M_PAD * 4);
  float* uvec           = (float*)alloc(EMB * 4);
  float* vvec           = (float*)alloc(EMB * 4);
  int* deg              = (int*)alloc((size_t)N_NODES * 4);
  int* rowstart         = (int*)alloc((size_t)N_NODES * 4);
  int* cursor           = (int*)alloc((size_t)N_NODES * 4);
  int* bsum             = (int*)alloc(256 * 4);
  int* csr_src          = (int*)alloc((size_t)N_EDGES * 4);
  (void)ws_size; (void)in_sizes; (void)n_in; (void)out_size;

  k_prep<<<dim3(2560), dim3(256), 0, stream>>>(W1, Wg, ln_g, ln_b, B1t, Wgp,
                                               uvec, vvec, deg, s1, s2);
  k_convhist<<<dim3(31280 + 3125), dim3(256), 0, stream>>>(features, featbf, dst, deg);
  k_scan1<<<dim3(196), dim3(256), 0, stream>>>(deg, rowstart, bsum);
  k_scan23<<<dim3(196), dim3(256), 0, stream>>>(bsum, rowstart, cursor);
  k_fill<<<dim3(3125), dim3(256), 0, stream>>>(src, dst, cursor, csr_src);
  k_gemm1<<<dim3(1564), dim3(256), 0, stream>>>(featbf, B1t, b1, xn, s1, s2);
  k_gemm2<<<dim3(MT1), dim3(256), 0, stream>>>(xn, Wgp, s1, s2, uvec, vvec,
                                               attn_l, attn_r, feat, el, er);
  k_gat<<<dim3(12500), dim3(256), 0, stream>>>(rowstart, deg, csr_src, el, er, feat, bias_g, out);
}

// Round 4
// 654.401 us; speedup vs baseline: 1.0625x; 1.0524x over previous
//
#include <hip/hip_runtime.h>
#include <hip/hip_bf16.h>
#include <stdint.h>

#define N_NODES 50000
#define N_EDGES 800000
#define IN_DIM 1280
#define HID 512
#define EMB 64
#define M_PAD 50176   // 196 * 256
#define MT1 391       // gemm2 M-tiles of 128 (covers 50048 >= N_NODES)
#define LN_EPS 1e-5f

typedef __attribute__((ext_vector_type(8))) __bf16 bf16x8;
typedef __attribute__((ext_vector_type(4))) float floatx4;

#define AS1C(p) ((const __attribute__((address_space(1))) void*)(p))
#define AS3(p)  ((__attribute__((address_space(3))) void*)(p))

__device__ __forceinline__ unsigned f2bf(float f) {
  unsigned u = __float_as_uint(f);
  u += 0x7FFFu + ((u >> 16) & 1u);
  return u >> 16;
}
__device__ __forceinline__ float bf2f(unsigned short s) {
  return __uint_as_float(((unsigned)s) << 16);
}

// ---------------- prep: weights -> bf16 transposed; LN-fold consts; zeros ------
__global__ __launch_bounds__(256) void k_prep(const float* __restrict__ W1,
                                              const float* __restrict__ Wg,
                                              const float* __restrict__ ln_g,
                                              const float* __restrict__ ln_b,
                                              unsigned short* __restrict__ B1t,
                                              unsigned short* __restrict__ Wgp,
                                              float* __restrict__ uvec,
                                              float* __restrict__ vvec,
                                              int* __restrict__ deg,
                                              float* __restrict__ s1,
                                              float* __restrict__ s2) {
  int idx = blockIdx.x * 256 + threadIdx.x;
  if (idx < HID * IN_DIM) {
    int n = idx / IN_DIM;
    int k = idx - n * IN_DIM;
    B1t[idx] = (unsigned short)f2bf(W1[(size_t)k * HID + n]);
  }
  if (idx < EMB * HID) {
    int n = idx >> 9;
    int k = idx & 511;
    Wgp[idx] = (unsigned short)f2bf(ln_g[k] * Wg[(size_t)k * EMB + n]);
  }
  if (idx < EMB) {
    float su = 0.f, sv = 0.f;
    for (int k = 0; k < HID; ++k) {
      float wv = Wg[(size_t)k * EMB + idx];
      su += ln_b[k] * wv;
      sv += ln_g[k] * wv;
    }
    uvec[idx] = su;
    vvec[idx] = sv;
  }
  if (idx < N_NODES) deg[idx] = 0;
  if (idx < M_PAD) { s1[idx] = 0.f; s2[idx] = 0.f; }
}

// ---------------- conv (features fp32->bf16, pad zero) + hist fused ------------
// 31360 conv blocks cover 50176 rows * 1280 cols / (256*8)
__global__ __launch_bounds__(256) void k_convhist(const float* __restrict__ F,
                                                  unsigned short* __restrict__ Fb,
                                                  const int* __restrict__ dst,
                                                  int* __restrict__ deg) {
  if (blockIdx.x < 31360) {
    size_t base = ((size_t)blockIdx.x * 256 + threadIdx.x) * 8;
    uint4 o;
    if (base < (size_t)N_NODES * IN_DIM) {
      float4 f0 = *(const float4*)(F + base);
      float4 f1 = *(const float4*)(F + base + 4);
      o.x = f2bf(f0.x) | (f2bf(f0.y) << 16);
      o.y = f2bf(f0.z) | (f2bf(f0.w) << 16);
      o.z = f2bf(f1.x) | (f2bf(f1.y) << 16);
      o.w = f2bf(f1.z) | (f2bf(f1.w) << 16);
    } else {
      o = make_uint4(0u, 0u, 0u, 0u);
    }
    *(uint4*)(Fb + base) = o;
  } else {
    int t = (blockIdx.x - 31360) * 256 + threadIdx.x;
    if (t < N_EDGES) atomicAdd(&deg[dst[t]], 1);
  }
}

// ---------------- GEMM1: 8-phase 256x128 port (m201-style) ---------------------
// BM=256 BN=128 BK=64, 512 thr (8 waves, 4M x 2N slabs of 64x64).
// LDS 128 KB dynamic: A 3-deep (32 KB each @ 0/32K/64K), B 2-deep (16 KB @ 96K/112K).
// Per tile t: 4 phases, each {ds_read subtile | stage unit -> barrier ->
// lgkmcnt(0) -> sched_barrier -> setprio(1) 8 MFMA setprio(0) -> barrier}.
// Stage order per wave/iter: B(t+1) [P0, 2 ld] then A(t+2) [P1+P2, 4 ld].
// Steady-state wait at P3: vmcnt(4) (newest 4 = A(t+2)) -> retires A(t+1),B(t+1).
// Never drains to 0 in the main loop (only it==18 drains for the final tile).
__global__ __launch_bounds__(512, 2) void k_gemm1(const unsigned short* __restrict__ Abf,
                                                  const unsigned short* __restrict__ Bt,
                                                  const float* __restrict__ bias1,
                                                  unsigned short* __restrict__ xn,
                                                  float* __restrict__ s1,
                                                  float* __restrict__ s2) {
  extern __shared__ char smem[];
  const int t = threadIdx.x;
  // chunked XCD swizzle, bijective: 784 blocks = 8 XCDs x 98
  const int o = blockIdx.x;
  const int lin = (o & 7) * 98 + (o >> 3);
  const int bm = lin >> 2, bn = lin & 3;
  const int w = t >> 6, lane = t & 63, quad = lane >> 4, lr = lane & 15;
  const int wm = (w >> 1) * 64;   // M slab
  const int wn = (w & 1) * 64;    // N slab
  const int l7 = lr & 7;

  floatx4 acc[4][4];
#pragma unroll
  for (int i = 0; i < 4; ++i)
#pragma unroll
    for (int j = 0; j < 4; ++j) acc[i][j] = (floatx4){0.f, 0.f, 0.f, 0.f};

  // staging addressing: chunk = row*8 + storecol, row = j*64 + (t>>3),
  // storecol = t&7, source chunk col = (t&7) ^ (row&7)
  const int rr = t >> 3;                  // 0..63
  const int cc = (t & 7) ^ (rr & 7);
  const unsigned short* aP[4];
  const unsigned short* bP[2];
#pragma unroll
  for (int j = 0; j < 4; ++j)
    aP[j] = Abf + (size_t)(bm * 256 + j * 64 + rr) * IN_DIM + cc * 8;
#pragma unroll
  for (int j = 0; j < 2; ++j)
    bP[j] = Bt + (size_t)(bn * 128 + j * 64 + rr) * IN_DIM + cc * 8;
  const int stoff = w * 1024;             // wave-uniform byte base inside 8KB unit

#define GL(gp, lp) __builtin_amdgcn_global_load_lds(AS1C(gp), AS3(lp), 16, 0, 0)
#define STAGE_A_FULL(k0, b3) do { \
    GL(aP[0] + (k0), smem + (b3) * 32768 + 0 * 8192 + stoff); \
    GL(aP[1] + (k0), smem + (b3) * 32768 + 1 * 8192 + stoff); \
    GL(aP[2] + (k0), smem + (b3) * 32768 + 2 * 8192 + stoff); \
    GL(aP[3] + (k0), smem + (b3) * 32768 + 3 * 8192 + stoff); } while (0)
#define STAGE_A_H0(k0, b3) do { \
    GL(aP[0] + (k0), smem + (b3) * 32768 + 0 * 8192 + stoff); \
    GL(aP[1] + (k0), smem + (b3) * 32768 + 1 * 8192 + stoff); } while (0)
#define STAGE_A_H1(k0, b3) do { \
    GL(aP[2] + (k0), smem + (b3) * 32768 + 2 * 8192 + stoff); \
    GL(aP[3] + (k0), smem + (b3) * 32768 + 3 * 8192 + stoff); } while (0)
#define STAGE_B2(k0, b2) do { \
    GL(bP[0] + (k0), smem + 98304 + (b2) * 16384 + 0 * 8192 + stoff); \
    GL(bP[1] + (k0), smem + 98304 + (b2) * 16384 + 1 * 8192 + stoff); } while (0)
#define PH_IN() do { asm volatile("" ::: "memory"); __builtin_amdgcn_s_barrier(); \
    asm volatile("s_waitcnt lgkmcnt(0)" ::: "memory"); \
    __builtin_amdgcn_sched_barrier(0); } while (0)
#define PH_OUT() do { asm volatile("" ::: "memory"); __builtin_amdgcn_s_barrier(); } while (0)
#define MFMA(a, b, c) __builtin_amdgcn_mfma_f32_16x16x32_bf16((a), (b), (c), 0, 0, 0)

  // prologue: A(0), B(0), A(1) -> 10 outstanding; wait oldest 6 (A0,B0)
  STAGE_A_FULL(0, 0);
  STAGE_B2(0, 0);
  STAGE_A_FULL(64, 1);
  asm volatile("s_waitcnt vmcnt(4)" ::: "memory");
  __builtin_amdgcn_s_barrier();
  asm volatile("" ::: "memory");

  for (int it = 0; it < 20; ++it) {
    const unsigned short* Ab = (const unsigned short*)(smem + (it % 3) * 32768);
    const unsigned short* Bb = (const unsigned short*)(smem + 98304 + (it & 1) * 16384);
    const int k2 = (it + 2) * 64;
    bf16x8 af[4], b0, b1;
    // ---- P0: A frags @kk0, B frags ni{0,1}@kk0; stage B(it+1)
    {
      const int cq = (quad ^ l7) * 8;
#pragma unroll
      for (int mi = 0; mi < 4; ++mi)
        af[mi] = *(const bf16x8*)&Ab[(wm + mi * 16 + lr) * 64 + cq];
      b0 = *(const bf16x8*)&Bb[(wn + 0 * 16 + lr) * 64 + cq];
      b1 = *(const bf16x8*)&Bb[(wn + 1 * 16 + lr) * 64 + cq];
      if (it + 1 < 20) STAGE_B2((it + 1) * 64, (it + 1) & 1);
      PH_IN();
      __builtin_amdgcn_s_setprio(1);
#pragma unroll
      for (int mi = 0; mi < 4; ++mi) {
        acc[mi][0] = MFMA(af[mi], b0, acc[mi][0]);
        acc[mi][1] = MFMA(af[mi], b1, acc[mi][1]);
      }
      __builtin_amdgcn_s_setprio(0);
      PH_OUT();
    }
    // ---- P1: B frags ni{2,3}@kk0 (af reused); stage A(it+2) half0
    {
      const int cq = (quad ^ l7) * 8;
      b0 = *(const bf16x8*)&Bb[(wn + 2 * 16 + lr) * 64 + cq];
      b1 = *(const bf16x8*)&Bb[(wn + 3 * 16 + lr) * 64 + cq];
      if (it + 2 < 20) STAGE_A_H0(k2, (it + 2) % 3);
      PH_IN();
      __builtin_amdgcn_s_setprio(1);
#pragma unroll
      for (int mi = 0; mi < 4; ++mi) {
        acc[mi][2] = MFMA(af[mi], b0, acc[mi][2]);
        acc[mi][3] = MFMA(af[mi], b1, acc[mi][3]);
      }
      __builtin_amdgcn_s_setprio(0);
      PH_OUT();
    }
    // ---- P2: A frags @kk1, B frags ni{0,1}@kk1; stage A(it+2) half1
    {
      const int cq = ((4 + quad) ^ l7) * 8;
#pragma unroll
      for (int mi = 0; mi < 4; ++mi)
        af[mi] = *(const bf16x8*)&Ab[(wm + mi * 16 + lr) * 64 + cq];
      b0 = *(const bf16x8*)&Bb[(wn + 0 * 16 + lr) * 64 + cq];
      b1 = *(const bf16x8*)&Bb[(wn + 1 * 16 + lr) * 64 + cq];
      if (it + 2 < 20) STAGE_A_H1(k2, (it + 2) % 3);
      PH_IN();
      __builtin_amdgcn_s_setprio(1);
#pragma unroll
      for (int mi = 0; mi < 4; ++mi) {
        acc[mi][0] = MFMA(af[mi], b0, acc[mi][0]);
        acc[mi][1] = MFMA(af[mi], b1, acc[mi][1]);
      }
      __builtin_amdgcn_s_setprio(0);
      PH_OUT();
    }
    // ---- P3: B frags ni{2,3}@kk1; per-tile counted vmcnt; trailing barrier
    {
      const int cq = ((4 + quad) ^ l7) * 8;
      b0 = *(const bf16x8*)&Bb[(wn + 2 * 16 + lr) * 64 + cq];
      b1 = *(const bf16x8*)&Bb[(wn + 3 * 16 + lr) * 64 + cq];
      PH_IN();
      __builtin_amdgcn_s_setprio(1);
#pragma unroll
      for (int mi = 0; mi < 4; ++mi) {
        acc[mi][2] = MFMA(af[mi], b0, acc[mi][2]);
        acc[mi][3] = MFMA(af[mi], b1, acc[mi][3]);
      }
      __builtin_amdgcn_s_setprio(0);
      if (it < 18) {
        asm volatile("s_waitcnt vmcnt(4)" ::: "memory");
      } else if (it == 18) {
        asm volatile("s_waitcnt vmcnt(0)" ::: "memory");
      }
      PH_OUT();
    }
  }
#undef GL
#undef STAGE_A_FULL
#undef STAGE_A_H0
#undef STAGE_A_H1
#undef STAGE_B2
#undef PH_IN
#undef PH_OUT
#undef MFMA

  // epilogue: bias + ReLU -> bf16 xn; per-row partial sums -> atomics
#pragma unroll
  for (int mi = 0; mi < 4; ++mi) {
    int gr = bm * 256 + wm + mi * 16 + quad * 4;
#pragma unroll
    for (int r = 0; r < 4; ++r) {
      float ps1 = 0.f, ps2 = 0.f;
#pragma unroll
      for (int ni = 0; ni < 4; ++ni) {
        int gc = bn * 128 + wn + ni * 16 + lr;
        float v = acc[mi][ni][r] + bias1[gc];
        v = v > 0.f ? v : 0.f;
        unsigned short h = (unsigned short)f2bf(v);
        xn[(size_t)(gr + r) * HID + gc] = h;
        float vr = bf2f(h);
        ps1 += vr;
        ps2 += vr * vr;
      }
#pragma unroll
      for (int m = 1; m < 16; m <<= 1) {
        ps1 += __shfl_xor(ps1, m, 64);
        ps2 += __shfl_xor(ps2, m, 64);
      }
      if (lr == 0) {
        atomicAdd(&s1[gr + r], ps1);
        atomicAdd(&s2[gr + r], ps2);
      }
    }
  }
}

// swizzle for BK=32 tiles (gemm2): chunk c of row r at c ^ swz(r), 4 chunks/row
__device__ __forceinline__ int swz(int r) { return (r ^ (r >> 2)) & 3; }

// ---------------- GEMM2 (LN folded) + fused el/er ------------------------------
__global__ __launch_bounds__(256) void k_gemm2(const unsigned short* __restrict__ Xn,
                                               const unsigned short* __restrict__ Wgp,
                                               const float* __restrict__ s1,
                                               const float* __restrict__ s2,
                                               const float* __restrict__ uvec,
                                               const float* __restrict__ vvec,
                                               const float* __restrict__ al,
                                               const float* __restrict__ ar,
                                               float* __restrict__ feat,
                                               float* __restrict__ el,
                                               float* __restrict__ er) {
  __shared__ unsigned short As[128 * 32];   // 8 KB
  __shared__ unsigned short Bs[64 * 32];    // 4 KB
  const int t = threadIdx.x;
  const int bm = blockIdx.x;
  const int w = t >> 6, lane = t & 63, quad = lane >> 4, lr = lane & 15;

  floatx4 acc[2][4];
#pragma unroll
  for (int i = 0; i < 2; ++i)
#pragma unroll
    for (int j = 0; j < 4; ++j) acc[i][j] = (floatx4){0.f, 0.f, 0.f, 0.f};

  const int r0 = t >> 2, c0 = (t & 3) ^ swz(t >> 2);
  const int r1 = 64 + (t >> 2), c1 = (t & 3) ^ swz(64 + (t >> 2));
  const unsigned short* a0 = Xn + (size_t)(bm * 128 + r0) * HID + c0 * 8;
  const unsigned short* a1 = Xn + (size_t)(bm * 128 + r1) * HID + c1 * 8;
  const unsigned short* b0 = Wgp + (size_t)r0 * HID + c0 * 8;
  unsigned short* asw = As + w * 512;
  unsigned short* bsw = Bs + w * 512;       // wave covers 1024 B

  const int q2 = quad ^ swz(lr);

  for (int k0 = 0; k0 < HID; k0 += 32) {
    __builtin_amdgcn_global_load_lds(AS1C(a0 + k0), AS3(asw), 16, 0, 0);
    __builtin_amdgcn_global_load_lds(AS1C(a1 + k0), AS3(asw + 2048), 16, 0, 0);
    __builtin_amdgcn_global_load_lds(AS1C(b0 + k0), AS3(bsw), 16, 0, 0);
    __syncthreads();

    bf16x8 af[2], bfv[4];
#pragma unroll
    for (int mi = 0; mi < 2; ++mi)
      af[mi] = *(const bf16x8*)&As[(w * 32 + mi * 16 + lr) * 32 + q2 * 8];
#pragma unroll
    for (int ni = 0; ni < 4; ++ni)
      bfv[ni] = *(const bf16x8*)&Bs[(ni * 16 + lr) * 32 + q2 * 8];
#pragma unroll
    for (int mi = 0; mi < 2; ++mi)
#pragma unroll
      for (int ni = 0; ni < 4; ++ni)
        acc[mi][ni] = __builtin_amdgcn_mfma_f32_16x16x32_bf16(af[mi], bfv[ni], acc[mi][ni], 0, 0, 0);
    __syncthreads();
  }

  float alv[4], arv[4], uv[4], vv[4];
#pragma unroll
  for (int ni = 0; ni < 4; ++ni) {
    alv[ni] = al[ni * 16 + lr];
    arv[ni] = ar[ni * 16 + lr];
    uv[ni] = uvec[ni * 16 + lr];
    vv[ni] = vvec[ni * 16 + lr];
  }
#pragma unroll
  for (int mi = 0; mi < 2; ++mi) {
    int gr = bm * 128 + w * 32 + mi * 16 + quad * 4;
#pragma unroll
    for (int r = 0; r < 4; ++r) {
      int row = gr + r;
      float mu = s1[row] * (1.f / HID);
      float rs = rsqrtf(s2[row] * (1.f / HID) - mu * mu + LN_EPS);
      float mrs = mu * rs;
      float sl = 0.f, sr2 = 0.f;
#pragma unroll
      for (int ni = 0; ni < 4; ++ni) {
        float v = rs * acc[mi][ni][r] + uv[ni] - mrs * vv[ni];
        feat[(size_t)row * EMB + ni * 16 + lr] = v;
        sl += v * alv[ni];
        sr2 += v * arv[ni];
      }
#pragma unroll
      for (int m = 1; m < 16; m <<= 1) {
        sl += __shfl_xor(sl, m, 64);
        sr2 += __shfl_xor(sr2, m, 64);
      }
      if (lr == 0) {
        el[row] = sl;
        er[row] = sr2;
      }
    }
  }
}

// ---------------- CSR build ----------------------------------------------------
__global__ __launch_bounds__(256) void k_scan1(const int* __restrict__ deg,
                                               int* __restrict__ rowstart,
                                               int* __restrict__ bsum) {
  __shared__ int sh[256];
  int t = threadIdx.x, i = blockIdx.x * 256 + t;
  int x = (i < N_NODES) ? deg[i] : 0;
  sh[t] = x;
  __syncthreads();
  for (int off = 1; off < 256; off <<= 1) {
    int v = (t >= off) ? sh[t - off] : 0;
    __syncthreads();
    sh[t] += v;
    __syncthreads();
  }
  if (i < N_NODES) rowstart[i] = sh[t] - x;
  if (t == 255) bsum[blockIdx.x] = sh[255];
}

__global__ __launch_bounds__(256) void k_scan23(const int* __restrict__ bsum,
                                                int* __restrict__ rowstart,
                                                int* __restrict__ cursor) {
  __shared__ int sh[256];
  int t = threadIdx.x;
  int x = (t < 196) ? bsum[t] : 0;
  sh[t] = x;
  __syncthreads();
  for (int off = 1; off < 256; off <<= 1) {
    int v = (t >= off) ? sh[t - off] : 0;
    __syncthreads();
    sh[t] += v;
    __syncthreads();
  }
  int boff = (blockIdx.x > 0) ? sh[blockIdx.x - 1] : 0;  // exclusive prefix
  __syncthreads();
  int i = blockIdx.x * 256 + t;
  if (i < N_NODES) {
    int rs = rowstart[i] + boff;
    rowstart[i] = rs;
    cursor[i] = rs;
  }
}

__global__ __launch_bounds__(256) void k_fill(const int* __restrict__ src,
                                              const int* __restrict__ dst,
                                              int* __restrict__ cursor,
                                              int* __restrict__ csr_src) {
  int t = blockIdx.x * 256 + threadIdx.x;
  if (t >= N_EDGES) return;
  int pos = atomicAdd(&cursor[dst[t]], 1);
  csr_src[pos] = src[t];
}

// ---------------- GAT aggregation, wave per node, no-max softmax ---------------
__global__ __launch_bounds__(256) void k_gat(const int* __restrict__ rowstart,
                                             const int* __restrict__ deg,
                                             const int* __restrict__ csr_src,
                                             const float* __restrict__ el,
                                             const float* __restrict__ er,
                                             const float* __restrict__ feat,
                                             const float* __restrict__ bias_g,
                                             float* __restrict__ out) {
  int w = threadIdx.x >> 6, lane = threadIdx.x & 63;
  int v = blockIdx.x * 4 + w;
  int start = rowstart[v], d = deg[v];
  float erv = er[v];
  float s = 0.f, O = 0.f;
#pragma unroll 4
  for (int i = 0; i < d; ++i) {
    int sv = csr_src[start + i];
    float f = feat[(size_t)sv * EMB + lane];
    float e = el[sv] + erv;
    e = e > 0.f ? e : 0.2f * e;
    float p = __expf(e);
    s += p;
    O = fmaf(p, f, O);
  }
  out[(size_t)v * EMB + lane] = (d > 0 ? O / s : 0.f) + bias_g[lane];
}

extern "C" void kernel_launch(void* const* d_in, const int* in_sizes, int n_in,
                              void* d_out, int out_size, void* d_ws, size_t ws_size,
                              hipStream_t stream) {
  const float* features = (const float*)d_in[0];
  const int* src        = (const int*)d_in[1];
  const int* dst        = (const int*)d_in[2];
  const float* W1       = (const float*)d_in[3];
  const float* b1       = (const float*)d_in[4];
  const float* ln_g     = (const float*)d_in[5];
  const float* ln_b     = (const float*)d_in[6];
  const float* Wg       = (const float*)d_in[7];
  const float* attn_l   = (const float*)d_in[8];
  const float* attn_r   = (const float*)d_in[9];
  const float* bias_g   = (const float*)d_in[10];
  float* out = (float*)d_out;

  char* ws = (char*)d_ws;
  size_t off = 0;
  auto alloc = [&](size_t bytes) {
    char* p = ws + off;
    off = (off + bytes + 255) & ~(size_t)255;
    return p;
  };
  unsigned short* B1t   = (unsigned short*)alloc((size_t)HID * IN_DIM * 2);
  unsigned short* Wgp   = (unsigned short*)alloc((size_t)EMB * HID * 2);
  unsigned short* featbf= (unsigned short*)alloc((size_t)M_PAD * IN_DIM * 2);
  unsigned short* xn    = (unsigned short*)alloc((size_t)M_PAD * HID * 2);
  float* feat           = (float*)alloc((size_t)M_PAD * EMB * 4);
  float* el             = (float*)alloc((size_t)M_PAD * 4);
  float* er             = (float*)alloc((size_t)M_PAD * 4);
  float* s1             = (float*)alloc((size_t)M_PAD * 4);
  float* s2             = (float*)alloc((size_t)M_PAD * 4);
  float* uvec           = (float*)alloc(EMB * 4);
  float* vvec           = (float*)alloc(EMB * 4);
  int* deg              = (int*)alloc((size_t)N_NODES * 4);
  int* rowstart         = (int*)alloc((size_t)N_NODES * 4);
  int* cursor           = (int*)alloc((size_t)N_NODES * 4);
  int* bsum             = (int*)alloc(256 * 4);
  int* csr_src          = (int*)alloc((size_t)N_EDGES * 4);
  (void)ws_size; (void)in_sizes; (void)n_in; (void)out_size;

  static int smem_set = 0;
  if (!smem_set) {
    hipFuncSetAttribute((const void*)k_gemm1,
                        hipFuncAttributeMaxDynamicSharedMemorySize, 131072);
    smem_set = 1;
  }

  k_prep<<<dim3(2560), dim3(256), 0, stream>>>(W1, Wg, ln_g, ln_b, B1t, Wgp,
                                               uvec, vvec, deg, s1, s2);
  k_convhist<<<dim3(31360 + 3125), dim3(256), 0, stream>>>(features, featbf, dst, deg);
  k_scan1<<<dim3(196), dim3(256), 0, stream>>>(deg, rowstart, bsum);
  k_scan23<<<dim3(196), dim3(256), 0, stream>>>(bsum, rowstart, cursor);
  k_fill<<<dim3(3125), dim3(256), 0, stream>>>(src, dst, cursor, csr_src);
  k_gemm1<<<dim3(784), dim3(512), 131072, stream>>>(featbf, B1t, b1, xn, s1, s2);
  k_gemm2<<<dim3(MT1), dim3(256), 0, stream>>>(xn, Wgp, s1, s2, uvec, vvec,
                                               attn_l, attn_r, feat, el, er);
  k_gat<<<dim3(12500), dim3(256), 0, stream>>>(rowstart, deg, csr_src, el, er, feat, bias_g, out);
}